// Round 17
// baseline (392.147 us; speedup 1.0000x reference)
//
#include <hip/hip_runtime.h>
#include <math.h>

// Swin block: B=8, C=256, H=W=128, WS=8, SS=4, NH=8, dh=32
// Weights frag-packed: wf[((tile*KT+kt)*64+l)*8+e] = W[tile*16+(l&15)][kt*32+(l>>4)*8+e]
// attn: x read once (reg stash), XCD swizzle, frag-packed h, v via in-reg shfl bridge
//       (no vT LDS round-trip). mlp: half-chunk pipeline, dbuf Mf, trimmed prefetch,
//       rcp-GELU hoisted into MFMA shadow.

#define LDH 264   // bf16 row stride for row-major [64][256] tiles (o, xsh)
#define LDS_S 40  // per-wave q/k slots [64][40]

typedef __attribute__((ext_vector_type(8))) short bf16x8;
typedef __attribute__((ext_vector_type(4))) short bf16x4;
typedef __attribute__((ext_vector_type(4))) float f32x4;

#define WF(wf, tile, KT, kt, ln) (*(const bf16x8*)&(wf)[((((tile)*(KT)) + (kt))*64 + (ln))*8])
#define FRAG(basep, ttile, KT, kt, l) (*(const bf16x8*)&(basep)[((((ttile)*(KT)) + (kt))*64 + (l))*8])

static __device__ __forceinline__ float bf2f(short s){
  union { unsigned u; float f; } cv;
  cv.u = ((unsigned)(unsigned short)s) << 16;
  return cv.f;
}
// native bf16 convert (RNE; clang lowers to v_cvt_pk_bf16_f32)
static __device__ __forceinline__ short f2bf(float f){
  __bf16 h = (__bf16)f;
  union { __bf16 b; short s; } cv; cv.b = h;
  return cv.s;
}
static __device__ __forceinline__ unsigned pk2bf(float lo, float hi){
  return (unsigned)(unsigned short)f2bf(lo) | ((unsigned)(unsigned short)f2bf(hi) << 16);
}
// tanh-form GELU via g = x*(1 - 1/(e+1)); NaN-safe; ~8 VALU ops.
static __device__ __forceinline__ float gelu_f(float x){
  const float x2 = x * x;
  const float u  = x * fmaf(0.0713537014f, x2, 1.5957691216f);
  const float e  = __expf(u);
  const float r  = __builtin_amdgcn_rcpf(e + 1.f);
  return x * (1.f - r);
}

// ---------------- K0: fp32 -> bf16 fragment-order repack ----------------
__global__ void wpack_kernel(const float* __restrict__ src, short* __restrict__ dst,
                             int K){
  const int t8 = blockIdx.x * 256 + threadIdx.x;
  const int e0 = t8 * 8;
  const int l   = (e0 >> 3) & 63;
  const int blk = e0 >> 9;
  const int KT  = K >> 5;
  const int kt   = blk % KT;
  const int tile = blk / KT;
  const int row = tile*16 + (l & 15);
  const int kb  = kt*32 + (l >> 4)*8;
  const float* s = src + row*K + kb;
  bf16x8 o;
  #pragma unroll
  for (int e=0;e<8;++e) o[e] = f2bf(s[e]);
  *(bf16x8*)&dst[e0] = o;
}

// ---------------- kernel 1: LN1 + QKV + attention + out-proj(swapped) -> win2T ----------------
#define K1_OFF_WV  33792
#define K1_OFF_RED 74752
#define K1_SMEM    76800

__global__ __launch_bounds__(256, 2)
void swin_attn_kernel(const float* __restrict__ x,
                      const float* __restrict__ ln1w, const float* __restrict__ ln1b,
                      const float* __restrict__ inb,  const float* __restrict__ outb,
                      const short* __restrict__ wqkv, const short* __restrict__ wout,
                      short* __restrict__ win2T)
{
  __shared__ char smem[K1_SMEM];
  short* shf    = (short*)smem;                 // h frag-packed (32768 B), then o row-major [64][264]
  short* sh_o   = (short*)smem;
  short* xsh    = (short*)(smem + K1_OFF_WV);   // x bf16 stash row-major (post-attention)
  float* red_s  = (float*)(smem + K1_OFF_RED);
  float* red_q2 = red_s + 256;

  const int tid = threadIdx.x;
  const int wv  = tid >> 6;
  const int ln  = tid & 63;
  const int rowa = ln & 15;
  const int kg   = ln >> 4;

  short* slotA = (short*)(smem + K1_OFF_WV) + wv*5120;
  short* slotB = slotA + 2560;

  const int bid = blockIdx.x;
  const int wi  = ((bid & 7) << 8) | (bid >> 3);   // XCD swizzle (2048%8==0, bijective)
  const int b  = wi >> 8;
  const int wh = (wi >> 4) & 15;
  const int ww = wi & 15;

  const int hh = (wh*8 + (ln >> 3) + 4) & 127;
  const int wc = (ww*8 + (ln & 7) + 4) & 127;
  const int offhw = hh*128 + wc;
  const int xbase = b << 22;

  unsigned xpk[32];
  {
    const int cbeg = wv*64;
    float vals[64];
    float s = 0.f, sq = 0.f;
    #pragma unroll
    for (int j = 0; j < 64; ++j){
      float v = x[xbase + ((cbeg + j) << 14) + offhw];
      vals[j] = v; s += v; sq += v*v;
    }
    #pragma unroll
    for (int p = 0; p < 32; ++p)
      xpk[p] = pk2bf(vals[2*p], vals[2*p+1]);
    red_s[cbeg + ln]  = s;
    red_q2[cbeg + ln] = sq;
    __syncthreads();
    float sum = red_s[ln] + red_s[64+ln] + red_s[128+ln] + red_s[192+ln];
    float ssq = red_q2[ln] + red_q2[64+ln] + red_q2[128+ln] + red_q2[192+ln];
    float mean = sum * 0.00390625f;
    float var  = ssq * 0.00390625f - mean*mean;
    float rstd = rsqrtf(var + 1e-5f);
    // h frag-packed write
    const int ttile = ln >> 4;
    #pragma unroll
    for (int kl=0;kl<2;++kl){
      const int kt = wv*2 + kl;
      #pragma unroll
      for (int kgw=0;kgw<4;++kgw){
        bf16x8 pkv;
        #pragma unroll
        for (int e=0;e<8;++e){
          const int j = kl*32 + kgw*8 + e;
          const int c = cbeg + j;
          pkv[e] = f2bf((vals[j] - mean) * rstd * ln1w[c] + ln1b[c]);
        }
        *(bf16x8*)&shf[(((ttile*8 + kt)*64) + kgw*16 + (ln & 15))*8] = pkv;
      }
    }
  }
  __syncthreads();

  const float scale = 0.1767766952966369f;
  f32x4 oacc[4][4];
  #pragma unroll
  for (int mt=0;mt<4;++mt)
    #pragma unroll
    for (int j=0;j<4;++j)
      oacc[mt][j] = (f32x4){0.f,0.f,0.f,0.f};

  const int s0 = ((kg & 1) << 5) + rowa;   // shfl bridge source-lane base

  #pragma unroll
  for (int hd = 0; hd < 2; ++hd){
    const int hc = (2*wv + hd) * 32;
    const int tq = (2*wv + hd) * 2;

    // ---- q + k fused (shared A-frags from frag-packed h) ----
    {
      f32x4 aq[4][2], ak[4][2];
      #pragma unroll
      for (int mt=0;mt<4;++mt){
        aq[mt][0]=(f32x4){0,0,0,0}; aq[mt][1]=(f32x4){0,0,0,0};
        ak[mt][0]=(f32x4){0,0,0,0}; ak[mt][1]=(f32x4){0,0,0,0};
      }
      #pragma unroll
      for (int kt=0;kt<8;++kt){
        bf16x8 av[4], bq[2], bk[2];
        #pragma unroll
        for (int mt=0;mt<4;++mt)
          av[mt] = FRAG(shf, mt, 8, kt, ln);
        #pragma unroll
        for (int nt=0;nt<2;++nt){
          bq[nt] = WF(wqkv, tq + nt,      8, kt, ln);
          bk[nt] = WF(wqkv, 16 + tq + nt, 8, kt, ln);
        }
        #pragma unroll
        for (int mt=0;mt<4;++mt)
          #pragma unroll
          for (int nt=0;nt<2;++nt){
            aq[mt][nt] = __builtin_amdgcn_mfma_f32_16x16x32_bf16(av[mt], bq[nt], aq[mt][nt], 0, 0, 0);
            ak[mt][nt] = __builtin_amdgcn_mfma_f32_16x16x32_bf16(av[mt], bk[nt], ak[mt][nt], 0, 0, 0);
          }
      }
      #pragma unroll
      for (int nt=0;nt<2;++nt){
        const float biasq = inb[hc + nt*16 + rowa];
        const float biask = inb[256 + hc + nt*16 + rowa];
        #pragma unroll
        for (int mt=0;mt<4;++mt)
          #pragma unroll
          for (int i=0;i<4;++i){
            slotA[(mt*16 + kg*4 + i)*LDS_S + nt*16 + rowa] = f2bf(aq[mt][nt][i] + biasq);
            slotB[(mt*16 + kg*4 + i)*LDS_S + nt*16 + rowa] = f2bf(ak[mt][nt][i] + biask);
          }
      }
    }

    // ---- S = q @ k^T ----
    f32x4 sacc[4][4];
    #pragma unroll
    for (int mt=0;mt<4;++mt)
      #pragma unroll
      for (int nt=0;nt<4;++nt)
        sacc[mt][nt] = (f32x4){0.f,0.f,0.f,0.f};
    {
      bf16x8 aq[4], bk[4];
      #pragma unroll
      for (int mt=0;mt<4;++mt)
        aq[mt] = *(const bf16x8*)&slotA[(mt*16+rowa)*LDS_S + kg*8];
      #pragma unroll
      for (int nt=0;nt<4;++nt)
        bk[nt] = *(const bf16x8*)&slotB[(nt*16+rowa)*LDS_S + kg*8];
      __builtin_amdgcn_s_setprio(1);
      #pragma unroll
      for (int mt=0;mt<4;++mt)
        #pragma unroll
        for (int nt=0;nt<4;++nt)
          sacc[mt][nt] = __builtin_amdgcn_mfma_f32_16x16x32_bf16(aq[mt], bk[nt], sacc[mt][nt], 0, 0, 0);
      __builtin_amdgcn_s_setprio(0);
    }

    // ---- v: GEMM -> bias -> packed pairs in regs (NO LDS; bridge below) ----
    unsigned pkv[4][2][2];   // [tok-tile mt][ch-tile nt][row-pair w]; pair = rows (kg*4+2w, +1)
    {
      f32x4 accv[4][2];
      #pragma unroll
      for (int mt=0;mt<4;++mt){ accv[mt][0]=(f32x4){0,0,0,0}; accv[mt][1]=(f32x4){0,0,0,0}; }
      #pragma unroll
      for (int kt=0;kt<8;++kt){
        bf16x8 av[4], bw[2];
        #pragma unroll
        for (int mt=0;mt<4;++mt)
          av[mt] = FRAG(shf, mt, 8, kt, ln);
        #pragma unroll
        for (int nt=0;nt<2;++nt)
          bw[nt] = WF(wqkv, 32 + tq + nt, 8, kt, ln);
        #pragma unroll
        for (int mt=0;mt<4;++mt)
          #pragma unroll
          for (int nt=0;nt<2;++nt)
            accv[mt][nt] = __builtin_amdgcn_mfma_f32_16x16x32_bf16(av[mt], bw[nt], accv[mt][nt], 0, 0, 0);
      }
      #pragma unroll
      for (int nt=0;nt<2;++nt){
        const float bias = inb[512 + hc + nt*16 + rowa];
        #pragma unroll
        for (int mt=0;mt<4;++mt){
          pkv[mt][nt][0] = pk2bf(accv[mt][nt][0] + bias, accv[mt][nt][1] + bias);
          pkv[mt][nt][1] = pk2bf(accv[mt][nt][2] + bias, accv[mt][nt][3] + bias);
        }
      }
    }

    // ---- softmax ----
    #pragma unroll
    for (int mt=0;mt<4;++mt){
      #pragma unroll
      for (int i=0;i<4;++i){
        float v0 = sacc[mt][0][i]*scale;
        float v1 = sacc[mt][1][i]*scale;
        float v2 = sacc[mt][2][i]*scale;
        float v3 = sacc[mt][3][i]*scale;
        float mx = fmaxf(fmaxf(v0,v1), fmaxf(v2,v3));
        #pragma unroll
        for (int d=1; d<16; d<<=1) mx = fmaxf(mx, __shfl_xor(mx, d, 64));
        v0 = __expf(v0-mx); v1 = __expf(v1-mx); v2 = __expf(v2-mx); v3 = __expf(v3-mx);
        float sm = v0+v1+v2+v3;
        #pragma unroll
        for (int d=1; d<16; d<<=1) sm += __shfl_xor(sm, d, 64);
        const float inv = 1.f / sm;
        sacc[mt][0][i] = v0*inv; sacc[mt][1][i] = v1*inv;
        sacc[mt][2][i] = v2*inv; sacc[mt][3][i] = v3*inv;
      }
    }

    // ---- PV in two kv-chunks of 32: P via slotA, V via in-register shfl bridge ----
    #pragma unroll
    for (int ck=0; ck<2; ++ck){
      #pragma unroll
      for (int ntl=0; ntl<2; ++ntl)
        #pragma unroll
        for (int mt=0;mt<4;++mt)
          #pragma unroll
          for (int i=0;i<4;++i)
            slotA[(mt*16 + kg*4 + i)*LDS_S + ntl*16 + rowa] = f2bf(sacc[mt][2*ck+ntl][i]);
      // v bridge: bv[nt] lane(rowa=ch-in-tile, k=tokk=ck*32+kg*8+e) from pkv D-layout
      bf16x8 bv[2];
      #pragma unroll
      for (int nt=0;nt<2;++nt){
        union { unsigned u[4]; bf16x8 v; } bb;
        #pragma unroll
        for (int dh2=0; dh2<2; ++dh2){
          #pragma unroll
          for (int w=0; w<2; ++w){
            const unsigned pe = (unsigned)__shfl((int)pkv[2*ck    ][nt][w], s0 + dh2*16);
            const unsigned po = (unsigned)__shfl((int)pkv[2*ck + 1][nt][w], s0 + dh2*16);
            bb.u[dh2*2 + w] = (kg & 2) ? po : pe;
          }
        }
        bv[nt] = bb.v;
      }
      bf16x8 ap[4];
      #pragma unroll
      for (int mt=0;mt<4;++mt)
        ap[mt] = *(const bf16x8*)&slotA[(mt*16+rowa)*LDS_S + kg*8];
      __builtin_amdgcn_s_setprio(1);
      #pragma unroll
      for (int mt=0;mt<4;++mt)
        #pragma unroll
        for (int nt=0;nt<2;++nt)
          oacc[mt][hd*2+nt] = __builtin_amdgcn_mfma_f32_16x16x32_bf16(ap[mt], bv[nt], oacc[mt][hd*2+nt], 0, 0, 0);
      __builtin_amdgcn_s_setprio(0);
    }
  }

  __syncthreads();   // done with h (shf) & slots -> sh_o row-major o, xsh x-stash

  #pragma unroll
  for (int j=0;j<4;++j){
    const int col = wv*64 + j*16 + rowa;
    #pragma unroll
    for (int mt=0;mt<4;++mt)
      #pragma unroll
      for (int i=0;i<4;++i)
        sh_o[(mt*16 + kg*4 + i)*LDH + col] = f2bf(oacc[mt][j][i]);
  }
  {
    const int cbeg = wv*64;
    #pragma unroll
    for (int q=0;q<8;++q){
      bf16x8 pk;
      #pragma unroll
      for (int e=0;e<4;++e){
        const unsigned w = xpk[q*4+e];
        pk[2*e]   = (short)(w & 0xffffu);
        pk[2*e+1] = (short)(w >> 16);
      }
      *(bf16x8*)&xsh[ln*LDH + cbeg + q*8] = pk;
    }
  }
  __syncthreads();

  // ---- out-proj SWAPPED: D'[ch][tok] = wout x o^T; + bias + x residual(LDS) -> win2T ----
  {
    f32x4 acc[4][4];
    #pragma unroll
    for (int c0=0;c0<4;++c0)
      #pragma unroll
      for (int t0=0;t0<4;++t0)
        acc[c0][t0] = (f32x4){0.f,0.f,0.f,0.f};
    for (int kt=0; kt<8; ++kt){
      bf16x8 aw[4], bo[4];
      #pragma unroll
      for (int c0=0;c0<4;++c0)
        aw[c0] = WF(wout, wv*4 + c0, 8, kt, ln);
      #pragma unroll
      for (int t0=0;t0<4;++t0)
        bo[t0] = *(const bf16x8*)&sh_o[(t0*16+rowa)*LDH + kt*32 + kg*8];
      #pragma unroll
      for (int c0=0;c0<4;++c0)
        #pragma unroll
        for (int t0=0;t0<4;++t0)
          acc[c0][t0] = __builtin_amdgcn_mfma_f32_16x16x32_bf16(aw[c0], bo[t0], acc[c0][t0], 0, 0, 0);
    }
    #pragma unroll
    for (int c0=0;c0<4;++c0){
      #pragma unroll
      for (int i=0;i<4;++i){
        const int ch = wv*64 + c0*16 + kg*4 + i;
        const float bias = outb[ch];
        #pragma unroll
        for (int t0=0;t0<4;++t0){
          const int tok = t0*16 + rowa;
          const float res = bf2f(xsh[tok*LDH + ch]);
          win2T[(wi<<14) + ch*64 + tok] = f2bf(acc[c0][t0][i] + bias + res);
        }
      }
    }
  }
}

// ---------------- kernel 2: LN2 + half-chunk pipelined MLP (dbuf Mf, hoisted gelu) ----
#define K2_OFF_M   32768
#define K2_OFF_RED 49152
#define K2_SMEM    51200

__device__ __forceinline__ void g1h_pre(const bf16x8 aw, const short* Yf,
                                        int kt, int ln, f32x4 acc1[4]){
  bf16x8 bh[4];
  #pragma unroll
  for (int ct=0;ct<4;++ct)
    bh[ct] = FRAG(Yf, ct, 8, kt, ln);
  #pragma unroll
  for (int ct=0;ct<4;++ct)
    acc1[ct] = __builtin_amdgcn_mfma_f32_16x16x32_bf16(aw, bh[ct], acc1[ct], 0, 0, 0);
}

__device__ __forceinline__ void g2h_pre(const short* Mfb, const bf16x8* w2c4,
                                        int kt2, int ln, f32x4 acc2[4][4]){
  bf16x8 bm[4];
  #pragma unroll
  for (int t0=0;t0<4;++t0)
    bm[t0] = FRAG(Mfb, t0, 2, kt2, ln);
  #pragma unroll
  for (int c0=0;c0<4;++c0)
    #pragma unroll
    for (int t0=0;t0<4;++t0)
      acc2[c0][t0] = __builtin_amdgcn_mfma_f32_16x16x32_bf16(w2c4[c0], bm[t0], acc2[c0][t0], 0, 0, 0);
}

__device__ __forceinline__ void gelu_pack(const float* __restrict__ b1p,
                                          const f32x4 acc1[4], bf16x4 stv[4]){
  const f32x4 b1v = *(const f32x4*)b1p;
  #pragma unroll
  for (int ct=0;ct<4;++ct){
    #pragma unroll
    for (int i=0;i<4;++i)
      stv[ct][i] = f2bf(gelu_f(acc1[ct][i] + b1v[i]));
  }
}

__device__ __forceinline__ void st_stv(short* Mfb, int wv, int rowa, int kg,
                                       const bf16x4 stv[4]){
  #pragma unroll
  for (int ct=0;ct<4;++ct)
    *(bf16x4*)&Mfb[(((ct*2 + (wv>>1))*64) + ((wv&1)*2 + (kg>>1))*16 + rowa)*8 + (kg&1)*4] = stv[ct];
}

__global__ __launch_bounds__(256, 3)
void swin_mlp_kernel(const short* __restrict__ win2T,
                     const float* __restrict__ ln2w, const float* __restrict__ ln2b,
                     const float* __restrict__ b1,   const float* __restrict__ b2,
                     const short* __restrict__ w1,   const short* __restrict__ w2,
                     float* __restrict__ out)
{
  __shared__ char smem[K2_SMEM];
  short* Yf  = (short*)smem;
  short* Mf0 = (short*)(smem + K2_OFF_M);
  short* Mf1 = Mf0 + 4096;
  float* red_s  = (float*)(smem + K2_OFF_RED);
  float* red_q2 = red_s + 256;

  const int tid = threadIdx.x;
  const int wv  = tid >> 6;
  const int ln  = tid & 63;
  const int rowa = ln & 15;
  const int kg   = ln >> 4;

  const int bid = blockIdx.x;
  const int wi  = ((bid & 7) << 8) | (bid >> 3);   // XCD swizzle
  const int wb = wi << 14;

  // ---- LN2 from win2T (coalesced rows) -> Yf frag-packed ----
  {
    float vals[64];
    float s = 0.f, sq = 0.f;
    const int cbeg = wv*64;
    #pragma unroll
    for (int j=0;j<64;++j){
      float v = bf2f(win2T[wb + (cbeg + j)*64 + ln]);
      vals[j] = v; s += v; sq += v*v;
    }
    red_s[cbeg + ln]  = s;
    red_q2[cbeg + ln] = sq;
    __syncthreads();
    float sum = red_s[ln] + red_s[64+ln] + red_s[128+ln] + red_s[192+ln];
    float ssq = red_q2[ln] + red_q2[64+ln] + red_q2[128+ln] + red_q2[192+ln];
    float mean = sum * 0.00390625f;
    float var  = ssq * 0.00390625f - mean*mean;
    float rstd = rsqrtf(var + 1e-5f);
    const int ttile = ln >> 4;
    #pragma unroll
    for (int kl=0;kl<2;++kl){
      const int kt = wv*2 + kl;
      #pragma unroll
      for (int kgw=0;kgw<4;++kgw){
        bf16x8 pkv;
        #pragma unroll
        for (int e=0;e<8;++e){
          const int j = kl*32 + kgw*8 + e;
          const int c = cbeg + j;
          pkv[e] = f2bf((vals[j] - mean) * rstd * ln2w[c] + ln2b[c]);
        }
        *(bf16x8*)&Yf[(((ttile*8 + kt)*64) + kgw*16 + (ln & 15))*8] = pkv;
      }
    }
  }
  __syncthreads();

  // ---- half-chunk pipeline; gelu+pack hoisted into G2b's MFMA shadow ----
  f32x4 acc2[4][4];
  #pragma unroll
  for (int c0=0;c0<4;++c0)
    #pragma unroll
    for (int t0=0;t0<4;++t0)
      acc2[c0][t0] = (f32x4){0.f,0.f,0.f,0.f};

  bf16x4 stv[4];
  {
    f32x4 acc1[4];
    #pragma unroll
    for (int ct=0;ct<4;++ct) acc1[ct] = (f32x4){0.f,0.f,0.f,0.f};
    #pragma unroll
    for (int kt=0;kt<8;++kt)
      g1h_pre(WF(w1, 0*4 + wv, 8, kt, ln), Yf, kt, ln, acc1);
    gelu_pack(&b1[wv*16 + kg*4], acc1, stv);
  }

  bf16x8 w1c[4];
  #pragma unroll
  for (int c = 0; c < 16; ++c){
    short* cur = (c & 1) ? Mf1 : Mf0;
    st_stv(cur, wv, rowa, kg, stv);

    bf16x8 w2c[8];
    #pragma unroll
    for (int j=0;j<8;++j)
      w2c[j] = WF(w2, wv*4 + (j & 3), 32, c*2 + (j >> 2), ln);
    if (c < 15){
      #pragma unroll
      for (int kt=0;kt<4;++kt)
        w1c[kt] = WF(w1, (c+1)*4 + wv, 8, kt, ln);
    }
    __syncthreads();   // Mf(c) published

    if (c < 15){
      f32x4 acc1n[4];
      #pragma unroll
      for (int ct=0;ct<4;++ct) acc1n[ct] = (f32x4){0.f,0.f,0.f,0.f};
      #pragma unroll
      for (int kt=0;kt<4;++kt) g1h_pre(w1c[kt], Yf, kt, ln, acc1n);
      g2h_pre(cur, &w2c[0], 0, ln, acc2);
      #pragma unroll
      for (int kt=4;kt<8;++kt)
        g1h_pre(WF(w1, (c+1)*4 + wv, 8, kt, ln), Yf, kt, ln, acc1n);
      gelu_pack(&b1[(c+1)*64 + wv*16 + kg*4], acc1n, stv);
      g2h_pre(cur, &w2c[4], 1, ln, acc2);
    } else {
      g2h_pre(cur, &w2c[0], 0, ln, acc2);
      g2h_pre(cur, &w2c[4], 1, ln, acc2);
    }
  }

  // ---- epilogue ----
  const int b  = wi >> 8;
  const int wh = (wi >> 4) & 15;
  const int ww = wi & 15;
  #pragma unroll
  for (int c0=0;c0<4;++c0){
    #pragma unroll
    for (int i=0;i<4;++i){
      const int ch = wv*64 + c0*16 + kg*4 + i;
      const float bias = b2[ch];
      #pragma unroll
      for (int t0=0;t0<4;++t0){
        const int tok = t0*16 + rowa;
        float v = acc2[c0][t0][i] + bias + bf2f(win2T[wb + ch*64 + tok]);
        const int r = tok >> 3, cw = tok & 7;
        const int hh = (wh*8 + r + 4) & 127;
        const int wcc = (ww*8 + cw + 4) & 127;
        out[(((b<<8) + ch) << 14) + hh*128 + wcc] = v;
      }
    }
  }
}

// ---------------- launch ----------------
extern "C" void kernel_launch(void* const* d_in, const int* in_sizes, int n_in,
                              void* d_out, int out_size, void* d_ws, size_t ws_size,
                              hipStream_t stream) {
  (void)in_sizes; (void)n_in; (void)out_size; (void)ws_size;
  const float* x    = (const float*)d_in[0];
  const float* ln1w = (const float*)d_in[1];
  const float* ln1b = (const float*)d_in[2];
  const float* inw  = (const float*)d_in[3];
  const float* inb  = (const float*)d_in[4];
  const float* outw = (const float*)d_in[5];
  const float* outb = (const float*)d_in[6];
  const float* ln2w = (const float*)d_in[7];
  const float* ln2b = (const float*)d_in[8];
  const float* w1f  = (const float*)d_in[9];
  const float* b1   = (const float*)d_in[10];
  const float* w2f  = (const float*)d_in[11];
  const float* b2   = (const float*)d_in[12];
  float* out = (float*)d_out;

  short* ws    = (short*)d_ws;
  short* wqkv  = ws;            // 768*256   (frag-packed, KT=8)
  short* wout  = ws + 196608;   // 256*256   (frag-packed, KT=8)
  short* w1b   = ws + 262144;   // 1024*256  (frag-packed, KT=8)
  short* w2b   = ws + 524288;   // 256*1024  (frag-packed, KT=32)
  short* win2T = ws + 786432;   // 2048 x 256ch x 64tok bf16

  hipLaunchKernelGGL(wpack_kernel, dim3(96),  dim3(256), 0, stream, inw,  wqkv, 256);
  hipLaunchKernelGGL(wpack_kernel, dim3(32),  dim3(256), 0, stream, outw, wout, 256);
  hipLaunchKernelGGL(wpack_kernel, dim3(128), dim3(256), 0, stream, w1f,  w1b,  256);
  hipLaunchKernelGGL(wpack_kernel, dim3(128), dim3(256), 0, stream, w2f,  w2b,  1024);

  hipLaunchKernelGGL(swin_attn_kernel, dim3(2048), dim3(256), 0, stream,
                     x, ln1w, ln1b, inb, outb, wqkv, wout, win2T);
  hipLaunchKernelGGL(swin_mlp_kernel, dim3(2048), dim3(256), 0, stream,
                     win2T, ln2w, ln2b, b1, b2, w1b, w2b, out);
}

// Round 18
// 358.016 us; speedup vs baseline: 1.0953x; 1.0953x over previous
//
#include <hip/hip_runtime.h>
#include <math.h>

// Swin block: B=8, C=256, H=W=128, WS=8, SS=4, NH=8, dh=32
// Weights frag-packed: wf[((tile*KT+kt)*64+l)*8+e] = W[tile*16+(l&15)][kt*32+(l>>4)*8+e]
// attn: x read once, XCD swizzle, frag-packed h, S^T operand swap (lane-local softmax),
//       P and V both via in-register shfl bridges (no P/vT LDS round-trips).
// mlp: half-chunk pipeline, dbuf Mf, trimmed prefetch, rcp-GELU in MFMA shadow.

#define LDH 264   // bf16 row stride for row-major [64][256] tiles (o, xsh)
#define LDS_S 40  // per-wave q/k slots [64][40]

typedef __attribute__((ext_vector_type(8))) short bf16x8;
typedef __attribute__((ext_vector_type(4))) short bf16x4;
typedef __attribute__((ext_vector_type(4))) float f32x4;

#define WF(wf, tile, KT, kt, ln) (*(const bf16x8*)&(wf)[((((tile)*(KT)) + (kt))*64 + (ln))*8])
#define FRAG(basep, ttile, KT, kt, l) (*(const bf16x8*)&(basep)[((((ttile)*(KT)) + (kt))*64 + (l))*8])

static __device__ __forceinline__ float bf2f(short s){
  union { unsigned u; float f; } cv;
  cv.u = ((unsigned)(unsigned short)s) << 16;
  return cv.f;
}
// native bf16 convert (RNE; clang lowers to v_cvt_pk_bf16_f32)
static __device__ __forceinline__ short f2bf(float f){
  __bf16 h = (__bf16)f;
  union { __bf16 b; short s; } cv; cv.b = h;
  return cv.s;
}
static __device__ __forceinline__ unsigned pk2bf(float lo, float hi){
  return (unsigned)(unsigned short)f2bf(lo) | ((unsigned)(unsigned short)f2bf(hi) << 16);
}
// tanh-form GELU via g = x*(1 - 1/(e+1)); NaN-safe; ~8 VALU ops.
static __device__ __forceinline__ float gelu_f(float x){
  const float x2 = x * x;
  const float u  = x * fmaf(0.0713537014f, x2, 1.5957691216f);
  const float e  = __expf(u);
  const float r  = __builtin_amdgcn_rcpf(e + 1.f);
  return x * (1.f - r);
}

// ---------------- K0: fp32 -> bf16 fragment-order repack ----------------
__global__ void wpack_kernel(const float* __restrict__ src, short* __restrict__ dst,
                             int K){
  const int t8 = blockIdx.x * 256 + threadIdx.x;
  const int e0 = t8 * 8;
  const int l   = (e0 >> 3) & 63;
  const int blk = e0 >> 9;
  const int KT  = K >> 5;
  const int kt   = blk % KT;
  const int tile = blk / KT;
  const int row = tile*16 + (l & 15);
  const int kb  = kt*32 + (l >> 4)*8;
  const float* s = src + row*K + kb;
  bf16x8 o;
  #pragma unroll
  for (int e=0;e<8;++e) o[e] = f2bf(s[e]);
  *(bf16x8*)&dst[e0] = o;
}

// ---------------- kernel 1: LN1 + QKV + attention(S^T) + out-proj(swapped) -> win2T -------
#define K1_OFF_WV  33792
#define K1_OFF_RED 74752
#define K1_SMEM    76800

__global__ __launch_bounds__(256, 2)
void swin_attn_kernel(const float* __restrict__ x,
                      const float* __restrict__ ln1w, const float* __restrict__ ln1b,
                      const float* __restrict__ inb,  const float* __restrict__ outb,
                      const short* __restrict__ wqkv, const short* __restrict__ wout,
                      short* __restrict__ win2T)
{
  __shared__ char smem[K1_SMEM];
  short* shf    = (short*)smem;                 // h frag-packed (32768 B), then o row-major [64][264]
  short* sh_o   = (short*)smem;
  short* xsh    = (short*)(smem + K1_OFF_WV);   // x bf16 stash row-major (post-attention)
  float* red_s  = (float*)(smem + K1_OFF_RED);
  float* red_q2 = red_s + 256;

  const int tid = threadIdx.x;
  const int wv  = tid >> 6;
  const int ln  = tid & 63;
  const int rowa = ln & 15;
  const int kg   = ln >> 4;

  short* slotA = (short*)(smem + K1_OFF_WV) + wv*5120;
  short* slotB = slotA + 2560;

  const int bid = blockIdx.x;
  const int wi  = ((bid & 7) << 8) | (bid >> 3);   // XCD swizzle (2048%8==0, bijective)
  const int b  = wi >> 8;
  const int wh = (wi >> 4) & 15;
  const int ww = wi & 15;

  const int hh = (wh*8 + (ln >> 3) + 4) & 127;
  const int wc = (ww*8 + (ln & 7) + 4) & 127;
  const int offhw = hh*128 + wc;
  const int xbase = b << 22;

  unsigned xpk[32];
  {
    const int cbeg = wv*64;
    float vals[64];
    float s = 0.f, sq = 0.f;
    #pragma unroll
    for (int j = 0; j < 64; ++j){
      float v = x[xbase + ((cbeg + j) << 14) + offhw];
      vals[j] = v; s += v; sq += v*v;
    }
    #pragma unroll
    for (int p = 0; p < 32; ++p)
      xpk[p] = pk2bf(vals[2*p], vals[2*p+1]);
    red_s[cbeg + ln]  = s;
    red_q2[cbeg + ln] = sq;
    __syncthreads();
    float sum = red_s[ln] + red_s[64+ln] + red_s[128+ln] + red_s[192+ln];
    float ssq = red_q2[ln] + red_q2[64+ln] + red_q2[128+ln] + red_q2[192+ln];
    float mean = sum * 0.00390625f;
    float var  = ssq * 0.00390625f - mean*mean;
    float rstd = rsqrtf(var + 1e-5f);
    // h frag-packed write
    const int ttile = ln >> 4;
    #pragma unroll
    for (int kl=0;kl<2;++kl){
      const int kt = wv*2 + kl;
      #pragma unroll
      for (int kgw=0;kgw<4;++kgw){
        bf16x8 pkv;
        #pragma unroll
        for (int e=0;e<8;++e){
          const int j = kl*32 + kgw*8 + e;
          const int c = cbeg + j;
          pkv[e] = f2bf((vals[j] - mean) * rstd * ln1w[c] + ln1b[c]);
        }
        *(bf16x8*)&shf[(((ttile*8 + kt)*64) + kgw*16 + (ln & 15))*8] = pkv;
      }
    }
  }
  __syncthreads();

  const float scale = 0.1767766952966369f;
  // O^T accumulator: [ch-tile (hd*2+c)][tok-tile ntq]; lane: ch row kg*4+i, tok col rowa
  f32x4 oaccT[4][4];
  #pragma unroll
  for (int c=0;c<4;++c)
    #pragma unroll
    for (int t=0;t<4;++t)
      oaccT[c][t] = (f32x4){0.f,0.f,0.f,0.f};

  const int s0 = ((kg & 1) << 5) + rowa;   // shfl bridge source-lane base

  #pragma unroll
  for (int hd = 0; hd < 2; ++hd){
    const int hc = (2*wv + hd) * 32;
    const int tq = (2*wv + hd) * 2;

    // ---- q + k fused (shared A-frags from frag-packed h) ----
    {
      f32x4 aq[4][2], ak[4][2];
      #pragma unroll
      for (int mt=0;mt<4;++mt){
        aq[mt][0]=(f32x4){0,0,0,0}; aq[mt][1]=(f32x4){0,0,0,0};
        ak[mt][0]=(f32x4){0,0,0,0}; ak[mt][1]=(f32x4){0,0,0,0};
      }
      #pragma unroll
      for (int kt=0;kt<8;++kt){
        bf16x8 av[4], bq[2], bk[2];
        #pragma unroll
        for (int mt=0;mt<4;++mt)
          av[mt] = FRAG(shf, mt, 8, kt, ln);
        #pragma unroll
        for (int nt=0;nt<2;++nt){
          bq[nt] = WF(wqkv, tq + nt,      8, kt, ln);
          bk[nt] = WF(wqkv, 16 + tq + nt, 8, kt, ln);
        }
        #pragma unroll
        for (int mt=0;mt<4;++mt)
          #pragma unroll
          for (int nt=0;nt<2;++nt){
            aq[mt][nt] = __builtin_amdgcn_mfma_f32_16x16x32_bf16(av[mt], bq[nt], aq[mt][nt], 0, 0, 0);
            ak[mt][nt] = __builtin_amdgcn_mfma_f32_16x16x32_bf16(av[mt], bk[nt], ak[mt][nt], 0, 0, 0);
          }
      }
      #pragma unroll
      for (int nt=0;nt<2;++nt){
        const float biasq = inb[hc + nt*16 + rowa];
        const float biask = inb[256 + hc + nt*16 + rowa];
        #pragma unroll
        for (int mt=0;mt<4;++mt)
          #pragma unroll
          for (int i=0;i<4;++i){
            slotA[(mt*16 + kg*4 + i)*LDS_S + nt*16 + rowa] = f2bf(aq[mt][nt][i] + biasq);
            slotB[(mt*16 + kg*4 + i)*LDS_S + nt*16 + rowa] = f2bf(ak[mt][nt][i] + biask);
          }
      }
    }

    // ---- S^T = k @ q^T (swapped): sacc[mtk(kv)][ntq(q)]; lane: kv row kg*4+i, q col rowa
    f32x4 sacc[4][4];
    #pragma unroll
    for (int mtk=0;mtk<4;++mtk)
      #pragma unroll
      for (int ntq=0;ntq<4;++ntq)
        sacc[mtk][ntq] = (f32x4){0.f,0.f,0.f,0.f};
    {
      bf16x8 akf[4], bqf[4];
      #pragma unroll
      for (int mtk=0;mtk<4;++mtk)
        akf[mtk] = *(const bf16x8*)&slotB[(mtk*16+rowa)*LDS_S + kg*8];
      #pragma unroll
      for (int ntq=0;ntq<4;++ntq)
        bqf[ntq] = *(const bf16x8*)&slotA[(ntq*16+rowa)*LDS_S + kg*8];
      __builtin_amdgcn_s_setprio(1);
      #pragma unroll
      for (int mtk=0;mtk<4;++mtk)
        #pragma unroll
        for (int ntq=0;ntq<4;++ntq)
          sacc[mtk][ntq] = __builtin_amdgcn_mfma_f32_16x16x32_bf16(akf[mtk], bqf[ntq], sacc[mtk][ntq], 0, 0, 0);
      __builtin_amdgcn_s_setprio(0);
    }

    // ---- v: GEMM -> bias -> packed pairs in regs (bridge feeds PV's A operand) ----
    unsigned pkv[4][2][2];   // [tok-tile mt][ch-tile nt][row-pair w]
    {
      f32x4 accv[4][2];
      #pragma unroll
      for (int mt=0;mt<4;++mt){ accv[mt][0]=(f32x4){0,0,0,0}; accv[mt][1]=(f32x4){0,0,0,0}; }
      #pragma unroll
      for (int kt=0;kt<8;++kt){
        bf16x8 av[4], bw[2];
        #pragma unroll
        for (int mt=0;mt<4;++mt)
          av[mt] = FRAG(shf, mt, 8, kt, ln);
        #pragma unroll
        for (int nt=0;nt<2;++nt)
          bw[nt] = WF(wqkv, 32 + tq + nt, 8, kt, ln);
        #pragma unroll
        for (int mt=0;mt<4;++mt)
          #pragma unroll
          for (int nt=0;nt<2;++nt)
            accv[mt][nt] = __builtin_amdgcn_mfma_f32_16x16x32_bf16(av[mt], bw[nt], accv[mt][nt], 0, 0, 0);
      }
      #pragma unroll
      for (int nt=0;nt<2;++nt){
        const float bias = inb[512 + hc + nt*16 + rowa];
        #pragma unroll
        for (int mt=0;mt<4;++mt){
          pkv[mt][nt][0] = pk2bf(accv[mt][nt][0] + bias, accv[mt][nt][1] + bias);
          pkv[mt][nt][1] = pk2bf(accv[mt][nt][2] + bias, accv[mt][nt][3] + bias);
        }
      }
    }

    // ---- softmax (transposed: q = ntq*16 + rowa; kv mostly lane-local) ----
    #pragma unroll
    for (int ntq=0;ntq<4;++ntq){
      float mx = sacc[0][ntq][0]*scale;
      #pragma unroll
      for (int mtk=0;mtk<4;++mtk)
        #pragma unroll
        for (int i=0;i<4;++i)
          mx = fmaxf(mx, sacc[mtk][ntq][i]*scale);
      mx = fmaxf(mx, __shfl_xor(mx, 16, 64));
      mx = fmaxf(mx, __shfl_xor(mx, 32, 64));
      float sm = 0.f;
      #pragma unroll
      for (int mtk=0;mtk<4;++mtk)
        #pragma unroll
        for (int i=0;i<4;++i){
          const float e = __expf(sacc[mtk][ntq][i]*scale - mx);
          sacc[mtk][ntq][i] = e; sm += e;
        }
      sm += __shfl_xor(sm, 16, 64);
      sm += __shfl_xor(sm, 32, 64);
      const float inv = 1.f / sm;
      #pragma unroll
      for (int mtk=0;mtk<4;++mtk)
        #pragma unroll
        for (int i=0;i<4;++i)
          sacc[mtk][ntq][i] *= inv;
    }

    // ---- PV (O^T): A = V^T via bridge, B = P^T via bridge; no LDS ----
    #pragma unroll
    for (int ck=0; ck<2; ++ck){
      // pack P^T pairs for the two kv tiles of this chunk
      unsigned pp[2][4][2];   // [mm = mtk-2ck][ntq][w]
      #pragma unroll
      for (int mm=0;mm<2;++mm)
        #pragma unroll
        for (int ntq=0;ntq<4;++ntq){
          pp[mm][ntq][0] = pk2bf(sacc[2*ck+mm][ntq][0], sacc[2*ck+mm][ntq][1]);
          pp[mm][ntq][1] = pk2bf(sacc[2*ck+mm][ntq][2], sacc[2*ck+mm][ntq][3]);
        }
      // A-frags: V^T ch-tiles c (lane: rowa=ch-in-tile, k=tok kv)
      bf16x8 avv[2];
      #pragma unroll
      for (int c=0;c<2;++c){
        union { unsigned u[4]; bf16x8 v; } bb;
        #pragma unroll
        for (int dh2=0; dh2<2; ++dh2){
          #pragma unroll
          for (int w=0; w<2; ++w){
            const unsigned pe = (unsigned)__shfl((int)pkv[2*ck    ][c][w], s0 + dh2*16);
            const unsigned po = (unsigned)__shfl((int)pkv[2*ck + 1][c][w], s0 + dh2*16);
            bb.u[dh2*2 + w] = (kg & 2) ? po : pe;
          }
        }
        avv[c] = bb.v;
      }
      // B-frags: P^T q-tiles ntq (lane: rowa=q, k=kv)
      bf16x8 bpf[4];
      #pragma unroll
      for (int ntq=0;ntq<4;++ntq){
        union { unsigned u[4]; bf16x8 v; } bb;
        #pragma unroll
        for (int d=0; d<4; ++d){
          const unsigned pe = (unsigned)__shfl((int)pp[0][ntq][d & 1], s0 + (d>>1)*16);
          const unsigned po = (unsigned)__shfl((int)pp[1][ntq][d & 1], s0 + (d>>1)*16);
          bb.u[d] = (kg & 2) ? po : pe;
        }
        bpf[ntq] = bb.v;
      }
      __builtin_amdgcn_s_setprio(1);
      #pragma unroll
      for (int c=0;c<2;++c)
        #pragma unroll
        for (int ntq=0;ntq<4;++ntq)
          oaccT[hd*2+c][ntq] = __builtin_amdgcn_mfma_f32_16x16x32_bf16(avv[c], bpf[ntq], oaccT[hd*2+c][ntq], 0, 0, 0);
      __builtin_amdgcn_s_setprio(0);
    }
  }

  __syncthreads();   // done with h (shf) & slots -> sh_o row-major o, xsh x-stash

  // o store from O^T: lane holds 4 consecutive ch per (c,t) -> b64 stores
  #pragma unroll
  for (int c=0;c<4;++c){
    const int chb = wv*64 + c*16 + kg*4;
    #pragma unroll
    for (int t=0;t<4;++t){
      bf16x4 st;
      #pragma unroll
      for (int i=0;i<4;++i) st[i] = f2bf(oaccT[c][t][i]);
      *(bf16x4*)&sh_o[(t*16 + rowa)*LDH + chb] = st;
    }
  }
  {
    const int cbeg = wv*64;
    #pragma unroll
    for (int q=0;q<8;++q){
      bf16x8 pk;
      #pragma unroll
      for (int e=0;e<4;++e){
        const unsigned w = xpk[q*4+e];
        pk[2*e]   = (short)(w & 0xffffu);
        pk[2*e+1] = (short)(w >> 16);
      }
      *(bf16x8*)&xsh[ln*LDH + cbeg + q*8] = pk;
    }
  }
  __syncthreads();

  // ---- out-proj SWAPPED: D'[ch][tok] = wout x o^T; + bias + x residual(LDS) -> win2T ----
  {
    f32x4 acc[4][4];
    #pragma unroll
    for (int c0=0;c0<4;++c0)
      #pragma unroll
      for (int t0=0;t0<4;++t0)
        acc[c0][t0] = (f32x4){0.f,0.f,0.f,0.f};
    for (int kt=0; kt<8; ++kt){
      bf16x8 aw[4], bo[4];
      #pragma unroll
      for (int c0=0;c0<4;++c0)
        aw[c0] = WF(wout, wv*4 + c0, 8, kt, ln);
      #pragma unroll
      for (int t0=0;t0<4;++t0)
        bo[t0] = *(const bf16x8*)&sh_o[(t0*16+rowa)*LDH + kt*32 + kg*8];
      #pragma unroll
      for (int c0=0;c0<4;++c0)
        #pragma unroll
        for (int t0=0;t0<4;++t0)
          acc[c0][t0] = __builtin_amdgcn_mfma_f32_16x16x32_bf16(aw[c0], bo[t0], acc[c0][t0], 0, 0, 0);
    }
    #pragma unroll
    for (int c0=0;c0<4;++c0){
      #pragma unroll
      for (int i=0;i<4;++i){
        const int ch = wv*64 + c0*16 + kg*4 + i;
        const float bias = outb[ch];
        #pragma unroll
        for (int t0=0;t0<4;++t0){
          const int tok = t0*16 + rowa;
          const float res = bf2f(xsh[tok*LDH + ch]);
          win2T[(wi<<14) + ch*64 + tok] = f2bf(acc[c0][t0][i] + bias + res);
        }
      }
    }
  }
}

// ---------------- kernel 2: LN2 + half-chunk pipelined MLP (dbuf Mf, hoisted gelu) ----
#define K2_OFF_M   32768
#define K2_OFF_RED 49152
#define K2_SMEM    51200

__device__ __forceinline__ void g1h_pre(const bf16x8 aw, const short* Yf,
                                        int kt, int ln, f32x4 acc1[4]){
  bf16x8 bh[4];
  #pragma unroll
  for (int ct=0;ct<4;++ct)
    bh[ct] = FRAG(Yf, ct, 8, kt, ln);
  #pragma unroll
  for (int ct=0;ct<4;++ct)
    acc1[ct] = __builtin_amdgcn_mfma_f32_16x16x32_bf16(aw, bh[ct], acc1[ct], 0, 0, 0);
}

__device__ __forceinline__ void g2h_pre(const short* Mfb, const bf16x8* w2c4,
                                        int kt2, int ln, f32x4 acc2[4][4]){
  bf16x8 bm[4];
  #pragma unroll
  for (int t0=0;t0<4;++t0)
    bm[t0] = FRAG(Mfb, t0, 2, kt2, ln);
  #pragma unroll
  for (int c0=0;c0<4;++c0)
    #pragma unroll
    for (int t0=0;t0<4;++t0)
      acc2[c0][t0] = __builtin_amdgcn_mfma_f32_16x16x32_bf16(w2c4[c0], bm[t0], acc2[c0][t0], 0, 0, 0);
}

__device__ __forceinline__ void gelu_pack(const float* __restrict__ b1p,
                                          const f32x4 acc1[4], bf16x4 stv[4]){
  const f32x4 b1v = *(const f32x4*)b1p;
  #pragma unroll
  for (int ct=0;ct<4;++ct){
    #pragma unroll
    for (int i=0;i<4;++i)
      stv[ct][i] = f2bf(gelu_f(acc1[ct][i] + b1v[i]));
  }
}

__device__ __forceinline__ void st_stv(short* Mfb, int wv, int rowa, int kg,
                                       const bf16x4 stv[4]){
  #pragma unroll
  for (int ct=0;ct<4;++ct)
    *(bf16x4*)&Mfb[(((ct*2 + (wv>>1))*64) + ((wv&1)*2 + (kg>>1))*16 + rowa)*8 + (kg&1)*4] = stv[ct];
}

__global__ __launch_bounds__(256, 3)
void swin_mlp_kernel(const short* __restrict__ win2T,
                     const float* __restrict__ ln2w, const float* __restrict__ ln2b,
                     const float* __restrict__ b1,   const float* __restrict__ b2,
                     const short* __restrict__ w1,   const short* __restrict__ w2,
                     float* __restrict__ out)
{
  __shared__ char smem[K2_SMEM];
  short* Yf  = (short*)smem;
  short* Mf0 = (short*)(smem + K2_OFF_M);
  short* Mf1 = Mf0 + 4096;
  float* red_s  = (float*)(smem + K2_OFF_RED);
  float* red_q2 = red_s + 256;

  const int tid = threadIdx.x;
  const int wv  = tid >> 6;
  const int ln  = tid & 63;
  const int rowa = ln & 15;
  const int kg   = ln >> 4;

  const int bid = blockIdx.x;
  const int wi  = ((bid & 7) << 8) | (bid >> 3);   // XCD swizzle
  const int wb = wi << 14;

  // ---- LN2 from win2T (coalesced rows) -> Yf frag-packed ----
  {
    float vals[64];
    float s = 0.f, sq = 0.f;
    const int cbeg = wv*64;
    #pragma unroll
    for (int j=0;j<64;++j){
      float v = bf2f(win2T[wb + (cbeg + j)*64 + ln]);
      vals[j] = v; s += v; sq += v*v;
    }
    red_s[cbeg + ln]  = s;
    red_q2[cbeg + ln] = sq;
    __syncthreads();
    float sum = red_s[ln] + red_s[64+ln] + red_s[128+ln] + red_s[192+ln];
    float ssq = red_q2[ln] + red_q2[64+ln] + red_q2[128+ln] + red_q2[192+ln];
    float mean = sum * 0.00390625f;
    float var  = ssq * 0.00390625f - mean*mean;
    float rstd = rsqrtf(var + 1e-5f);
    const int ttile = ln >> 4;
    #pragma unroll
    for (int kl=0;kl<2;++kl){
      const int kt = wv*2 + kl;
      #pragma unroll
      for (int kgw=0;kgw<4;++kgw){
        bf16x8 pkv;
        #pragma unroll
        for (int e=0;e<8;++e){
          const int j = kl*32 + kgw*8 + e;
          const int c = cbeg + j;
          pkv[e] = f2bf((vals[j] - mean) * rstd * ln2w[c] + ln2b[c]);
        }
        *(bf16x8*)&Yf[(((ttile*8 + kt)*64) + kgw*16 + (ln & 15))*8] = pkv;
      }
    }
  }
  __syncthreads();

  // ---- half-chunk pipeline; gelu+pack hoisted into G2b's MFMA shadow ----
  f32x4 acc2[4][4];
  #pragma unroll
  for (int c0=0;c0<4;++c0)
    #pragma unroll
    for (int t0=0;t0<4;++t0)
      acc2[c0][t0] = (f32x4){0.f,0.f,0.f,0.f};

  bf16x4 stv[4];
  {
    f32x4 acc1[4];
    #pragma unroll
    for (int ct=0;ct<4;++ct) acc1[ct] = (f32x4){0.f,0.f,0.f,0.f};
    #pragma unroll
    for (int kt=0;kt<8;++kt)
      g1h_pre(WF(w1, 0*4 + wv, 8, kt, ln), Yf, kt, ln, acc1);
    gelu_pack(&b1[wv*16 + kg*4], acc1, stv);
  }

  bf16x8 w1c[4];
  #pragma unroll
  for (int c = 0; c < 16; ++c){
    short* cur = (c & 1) ? Mf1 : Mf0;
    st_stv(cur, wv, rowa, kg, stv);

    bf16x8 w2c[8];
    #pragma unroll
    for (int j=0;j<8;++j)
      w2c[j] = WF(w2, wv*4 + (j & 3), 32, c*2 + (j >> 2), ln);
    if (c < 15){
      #pragma unroll
      for (int kt=0;kt<4;++kt)
        w1c[kt] = WF(w1, (c+1)*4 + wv, 8, kt, ln);
    }
    __syncthreads();   // Mf(c) published

    if (c < 15){
      f32x4 acc1n[4];
      #pragma unroll
      for (int ct=0;ct<4;++ct) acc1n[ct] = (f32x4){0.f,0.f,0.f,0.f};
      #pragma unroll
      for (int kt=0;kt<4;++kt) g1h_pre(w1c[kt], Yf, kt, ln, acc1n);
      g2h_pre(cur, &w2c[0], 0, ln, acc2);
      #pragma unroll
      for (int kt=4;kt<8;++kt)
        g1h_pre(WF(w1, (c+1)*4 + wv, 8, kt, ln), Yf, kt, ln, acc1n);
      gelu_pack(&b1[(c+1)*64 + wv*16 + kg*4], acc1n, stv);
      g2h_pre(cur, &w2c[4], 1, ln, acc2);
    } else {
      g2h_pre(cur, &w2c[0], 0, ln, acc2);
      g2h_pre(cur, &w2c[4], 1, ln, acc2);
    }
  }

  // ---- epilogue ----
  const int b  = wi >> 8;
  const int wh = (wi >> 4) & 15;
  const int ww = wi & 15;
  #pragma unroll
  for (int c0=0;c0<4;++c0){
    #pragma unroll
    for (int i=0;i<4;++i){
      const int ch = wv*64 + c0*16 + kg*4 + i;
      const float bias = b2[ch];
      #pragma unroll
      for (int t0=0;t0<4;++t0){
        const int tok = t0*16 + rowa;
        float v = acc2[c0][t0][i] + bias + bf2f(win2T[wb + ch*64 + tok]);
        const int r = tok >> 3, cw = tok & 7;
        const int hh = (wh*8 + r + 4) & 127;
        const int wcc = (ww*8 + cw + 4) & 127;
        out[(((b<<8) + ch) << 14) + hh*128 + wcc] = v;
      }
    }
  }
}

// ---------------- launch ----------------
extern "C" void kernel_launch(void* const* d_in, const int* in_sizes, int n_in,
                              void* d_out, int out_size, void* d_ws, size_t ws_size,
                              hipStream_t stream) {
  (void)in_sizes; (void)n_in; (void)out_size; (void)ws_size;
  const float* x    = (const float*)d_in[0];
  const float* ln1w = (const float*)d_in[1];
  const float* ln1b = (const float*)d_in[2];
  const float* inw  = (const float*)d_in[3];
  const float* inb  = (const float*)d_in[4];
  const float* outw = (const float*)d_in[5];
  const float* outb = (const float*)d_in[6];
  const float* ln2w = (const float*)d_in[7];
  const float* ln2b = (const float*)d_in[8];
  const float* w1f  = (const float*)d_in[9];
  const float* b1   = (const float*)d_in[10];
  const float* w2f  = (const float*)d_in[11];
  const float* b2   = (const float*)d_in[12];
  float* out = (float*)d_out;

  short* ws    = (short*)d_ws;
  short* wqkv  = ws;            // 768*256   (frag-packed, KT=8)
  short* wout  = ws + 196608;   // 256*256   (frag-packed, KT=8)
  short* w1b   = ws + 262144;   // 1024*256  (frag-packed, KT=8)
  short* w2b   = ws + 524288;   // 256*1024  (frag-packed, KT=32)
  short* win2T = ws + 786432;   // 2048 x 256ch x 64tok bf16

  hipLaunchKernelGGL(wpack_kernel, dim3(96),  dim3(256), 0, stream, inw,  wqkv, 256);
  hipLaunchKernelGGL(wpack_kernel, dim3(32),  dim3(256), 0, stream, outw, wout, 256);
  hipLaunchKernelGGL(wpack_kernel, dim3(128), dim3(256), 0, stream, w1f,  w1b,  256);
  hipLaunchKernelGGL(wpack_kernel, dim3(128), dim3(256), 0, stream, w2f,  w2b,  1024);

  hipLaunchKernelGGL(swin_attn_kernel, dim3(2048), dim3(256), 0, stream,
                     x, ln1w, ln1b, inb, outb, wqkv, wout, win2T);
  hipLaunchKernelGGL(swin_mlp_kernel, dim3(2048), dim3(256), 0, stream,
                     win2T, ln2w, ln2b, b1, b2, w1b, w2b, out);
}